// Round 9
// baseline (115.334 us; speedup 1.0000x reference)
//
#include <hip/hip_runtime.h>
#include <hip/hip_bf16.h>

// out[b,n] = sum_k x[b,k] * M[k,n],  M[k,n] = sign(k, k^n) * w[k^n]
// P=6,Q=0,R=0 -> metric all +1, sign = reorder parity only.
//
// out^T = M^T (A) @ x^T (B) via mfma_f32_16x16x32_bf16 (layout validated
// round 4, absmax 0.25):
//   A-frag: lane l -> row a=l&15, k=(l>>4)*8+e  (frag-ordered in d_ws)
//   B-frag: lane l -> col b=l&15, k=(l>>4)*8+e  = 8 contiguous k of x row b
//   C/D   : D[m=(l>>4)*4+reg][n=l&15] -> lane's 4 regs = 4 consecutive out
//           cols of one batch row.
//
// Round 9: multi-tile blocks (8 tiles x 64 rows), double-buffered LDS,
// COUNTED vmcnt (raw s_barrier + asm s_waitcnt, never 0 mid-loop; m201
// pattern) so DMA for tile t+2 stays in flight across tile t's compute.
// vmcnt bookkeeping (in-order retirement; 4 loads/tile, 4 stores/tile
// per thread):  iter t waits for loads(t); younger ops = stores(t-1)+
// loads(t+1) = 8 (t=0: just loads(1)=4; t=last: just stores=4).

#define DIM 64
#define TPB 256            // 4 waves
#define ROWS 64            // rows per tile; 16 KB per buffer
#define NT   8             // tiles per block

typedef __attribute__((ext_vector_type(8))) short  bf16x8;
typedef __attribute__((ext_vector_type(4))) float  f32x4;

typedef const unsigned int __attribute__((address_space(1)))* gu32p;
typedef unsigned int __attribute__((address_space(3)))* su32p;

__device__ __forceinline__ unsigned short f2bf(float v) {
    __hip_bfloat16 hb = __float2bfloat16(v);
    return *reinterpret_cast<unsigned short*>(&hb);
}

// Mt[(kc*4+ab)*64 + lane] = 16B A-fragment slice for mfma block (kc, ab):
// elem e -> A[a = ab*16 + (l&15)][k = kc*32 + (l>>4)*8 + e], A = M^T.
__global__ void build_Mt(const float* __restrict__ w, unsigned short* __restrict__ Mt) {
    int t = threadIdx.x + blockIdx.x * blockDim.x;   // 0..4095
    if (t >= 8 * 64 * 8) return;
    int f  = t >> 9;
    int kc = f >> 2, ab = f & 3;
    int rem = t & 511;
    int l = rem >> 3, e = rem & 7;
    int k = kc * 32 + ((l >> 4) << 3) + e;
    int a = (ab << 4) + (l & 15);
    int j = k ^ a;
    int aa = k >> 1, cnt = 0;
    while (aa) { cnt += __popc(aa & j); aa >>= 1; }
    float v = (cnt & 1) ? -w[j] : w[j];
    Mt[t] = f2bf(v);
}

__global__ __launch_bounds__(TPB, 5)   // 32KB LDS -> 5 blocks/CU = 20 waves
void gp_main_kernel(const float* __restrict__ x,
                    const unsigned short* __restrict__ Mt,
                    float* __restrict__ out) {
    __shared__ float xs[2][ROWS * DIM];  // 2 x 16 KB, granule-swizzled rows

    const int tid  = threadIdx.x;
    const int lane = tid & 63;
    const int wv   = tid >> 6;
    const int r15  = lane & 15;
    const int g    = lane >> 4;          // k-quarter within fragment

    const long long tile0 = (long long)blockIdx.x * NT;
    const float4* __restrict__ xin = (const float4*)x;
    float4* __restrict__ outp = (float4*)out;

    // ---- A-fragments (tiny, L1/L2-resident) ----
    bf16x8 af[2][4];
    const bf16x8* __restrict__ Mtv = (const bf16x8*)Mt;
    #pragma unroll
    for (int kc = 0; kc < 2; ++kc)
        #pragma unroll
        for (int ab = 0; ab < 4; ++ab)
            af[kc][ab] = Mtv[(kc * 4 + ab) * 64 + lane];

    // stage tile (tile0+t) into xs[buf]: linear LDS dest, pre-swizzled
    // global source (granule c = gr ^ (row&7), involution) - m104/m173
    auto STAGE = [&](int t, int buf) {
        #pragma unroll
        for (int it = 0; it < 4; ++it) {
            int idx  = it * TPB + tid;        // 0..1023 float4 slots
            int row  = idx >> 4;
            int f4   = idx & 15;
            int c    = ((f4 >> 1) ^ (row & 7));
            long long src = ((tile0 + t) * ROWS + row) * 16 + c * 2 + (f4 & 1);
            __builtin_amdgcn_global_load_lds((gu32p)(xin + src),
                                             (su32p)&xs[buf][idx * 4], 16, 0, 0);
        }
    };

    STAGE(0, 0);
    STAGE(1, 1);

    #pragma unroll
    for (int t = 0; t < NT; ++t) {
        const int cur = t & 1;
        // wait for own tile-t loads (counted; never drains the pipeline)
        if (t == 0 || t == NT - 1) asm volatile("s_waitcnt vmcnt(4)" ::: "memory");
        else                       asm volatile("s_waitcnt vmcnt(8)" ::: "memory");
        __builtin_amdgcn_s_barrier();             // all waves' tile-t DMA landed
        __builtin_amdgcn_sched_barrier(0);        // pin ds_read below barrier

        // ---- compute: wave wv owns rows [wv*16, wv*16+16) of the tile ----
        const int r_loc = wv * 16 + r15;
        bf16x8 bfr[2];
        #pragma unroll
        for (int kc = 0; kc < 2; ++kc) {
            int s = (kc * 4 + g) ^ (r_loc & 7);   // swizzled 32B granule
            const float* src = &xs[cur][r_loc * DIM + s * 8];
            float4 lo = *reinterpret_cast<const float4*>(src);       // ds_read_b128
            float4 hi = *reinterpret_cast<const float4*>(src + 4);   // ds_read_b128
            bf16x8 tt;
            tt[0] = (short)f2bf(lo.x); tt[1] = (short)f2bf(lo.y);
            tt[2] = (short)f2bf(lo.z); tt[3] = (short)f2bf(lo.w);
            tt[4] = (short)f2bf(hi.x); tt[5] = (short)f2bf(hi.y);
            tt[6] = (short)f2bf(hi.z); tt[7] = (short)f2bf(hi.w);
            bfr[kc] = tt;
        }

        f32x4 acc[4];
        #pragma unroll
        for (int ab = 0; ab < 4; ++ab) acc[ab] = (f32x4){0.f, 0.f, 0.f, 0.f};
        #pragma unroll
        for (int kc = 0; kc < 2; ++kc)
            #pragma unroll
            for (int ab = 0; ab < 4; ++ab)
                acc[ab] = __builtin_amdgcn_mfma_f32_16x16x32_bf16(
                    af[kc][ab], bfr[kc], acc[ab], 0, 0, 0);

        // ---- store (plain; nt regressed in round 8) ----
        const long long rg = (tile0 + t) * ROWS + r_loc;
        #pragma unroll
        for (int ab = 0; ab < 4; ++ab)
            outp[rg * 16 + ab * 4 + g] =
                make_float4(acc[ab][0], acc[ab][1], acc[ab][2], acc[ab][3]);

        __builtin_amdgcn_s_barrier();             // all waves done reading xs[cur]
        __builtin_amdgcn_sched_barrier(0);        // pin re-STAGE below barrier
        if (t + 2 < NT) STAGE(t + 2, cur);        // refill the consumed buffer
    }
}

extern "C" void kernel_launch(void* const* d_in, const int* in_sizes, int n_in,
                              void* d_out, int out_size, void* d_ws, size_t ws_size,
                              hipStream_t stream) {
    const float* x = (const float*)d_in[0];
    const float* w = (const float*)d_in[1];
    float* out = (float*)d_out;
    unsigned short* Mt = (unsigned short*)d_ws;   // 8 KB frag-ordered M^T

    int nrows = in_sizes[0] / DIM;                // 1048576
    int nblocks = nrows / (ROWS * NT);            // 2048 (exact)

    build_Mt<<<16, 256, 0, stream>>>(w, Mt);
    gp_main_kernel<<<nblocks, TPB, 0, stream>>>(x, Mt, out);
}

// Round 10
// 107.504 us; speedup vs baseline: 1.0728x; 1.0728x over previous
//
#include <hip/hip_runtime.h>
#include <hip/hip_bf16.h>

// out[b,n] = sum_k x[b,k] * M[k,n],  M[k,n] = sign(k, k^n) * w[k^n]
// P=6,Q=0,R=0 -> metric all +1, sign = reorder parity only.
//
// out^T = M^T (A) @ x^T (B) via mfma_f32_16x16x32_bf16 (layout validated
// round 4, absmax 0.25):
//   A-frag: lane l -> row a=l&15, k=(l>>4)*8+e  (frag-ordered in d_ws)
//   B-frag: lane l -> col b=l&15, k=(l>>4)*8+e  = 8 contiguous k of x row b
//   C/D   : D[m=(l>>4)*4+reg][n=l&15] -> lane's 4 regs = 4 consecutive out
//           cols of one batch row; 16-lane groups complete full 64B lines.
//
// Round 10: BARRIER-FREE round 6. Each wave DMA-stages only its OWN 16 rows
// into a private 4KB LDS region (global_load_lds dest = wave-uniform base +
// lane*16B, m104; swizzle applied on the GLOBAL source, m173), then waits on
// its own vmcnt only. No __syncthreads, no inter-wave coupling: waves start
// computing as soon as their own loads land and retire independently.
// (Round 9 showed deep pipelining + occupancy loss regresses; round 8 showed
// nt stores regress. This keeps 16KB LDS -> 8 blocks/CU = 32 waves/CU.)

#define DIM 64
#define TPB 256            // 4 independent waves
#define ROWS 64            // rows per block (16 per wave); LDS = 16 KB

typedef __attribute__((ext_vector_type(8))) short  bf16x8;
typedef __attribute__((ext_vector_type(4))) float  f32x4;

typedef const unsigned int __attribute__((address_space(1)))* gu32p;
typedef unsigned int __attribute__((address_space(3)))* su32p;

__device__ __forceinline__ unsigned short f2bf(float v) {
    __hip_bfloat16 hb = __float2bfloat16(v);
    return *reinterpret_cast<unsigned short*>(&hb);
}

// Mt[(kc*4+ab)*64 + lane] = 16B A-fragment slice for mfma block (kc, ab):
// elem e -> A[a = ab*16 + (l&15)][k = kc*32 + (l>>4)*8 + e], A = M^T.
__global__ void build_Mt(const float* __restrict__ w, unsigned short* __restrict__ Mt) {
    int t = threadIdx.x + blockIdx.x * blockDim.x;   // 0..4095
    if (t >= 8 * 64 * 8) return;
    int f  = t >> 9;
    int kc = f >> 2, ab = f & 3;
    int rem = t & 511;
    int l = rem >> 3, e = rem & 7;
    int k = kc * 32 + ((l >> 4) << 3) + e;
    int a = (ab << 4) + (l & 15);
    int j = k ^ a;
    int aa = k >> 1, cnt = 0;
    while (aa) { cnt += __popc(aa & j); aa >>= 1; }
    float v = (cnt & 1) ? -w[j] : w[j];
    Mt[t] = f2bf(v);
}

__global__ __launch_bounds__(TPB, 8)   // 8 blocks/CU = 32 waves/CU (VGPR<=64)
void gp_main_kernel(const float* __restrict__ x,
                    const unsigned short* __restrict__ Mt,
                    float* __restrict__ out) {
    __shared__ float xs[ROWS * DIM];     // 16 KB = 4 x 4KB wave-private regions

    const int tid  = threadIdx.x;
    const int lane = tid & 63;
    const int wv   = tid >> 6;
    const int r15  = lane & 15;
    const int g    = lane >> 4;          // k-quarter within fragment

    const long long rowbase = (long long)blockIdx.x * ROWS + (long long)wv * 16;
    const float4* __restrict__ xin = (const float4*)x;
    float* __restrict__ reg = &xs[wv * 16 * DIM];   // this wave's 4KB region

    // ---- stage own 16 rows: 4x global_load_lds dwordx4, private region ----
    // region f4-slot idx: local row r=idx>>4, pos f4=idx&15; content = source
    // granule c = (f4>>1) ^ (r&7)  (involution), half = f4&1.
    #pragma unroll
    for (int it = 0; it < 4; ++it) {
        int idx = it * 64 + lane;            // 0..255 f4 slots in region
        int r   = idx >> 4;
        int f4  = idx & 15;
        int c   = ((f4 >> 1) ^ (r & 7));
        long long src = (rowbase + r) * 16 + c * 2 + (f4 & 1);
        __builtin_amdgcn_global_load_lds((gu32p)(xin + src),
                                         (su32p)&reg[idx * 4], 16, 0, 0);
    }

    // ---- A-fragments (tiny, L2-resident) while DMA is in flight ----
    bf16x8 af[2][4];
    const bf16x8* __restrict__ Mtv = (const bf16x8*)Mt;
    #pragma unroll
    for (int kc = 0; kc < 2; ++kc)
        #pragma unroll
        for (int ab = 0; ab < 4; ++ab)
            af[kc][ab] = Mtv[(kc * 4 + ab) * 64 + lane];

    // per-wave drain of own DMA (+Mt loads, L2-fast). No barrier.
    asm volatile("s_waitcnt vmcnt(0)" ::: "memory");
    __builtin_amdgcn_sched_barrier(0);

    // ---- compute own rows: local row = r15 ----
    bf16x8 bfr[2];
    #pragma unroll
    for (int kc = 0; kc < 2; ++kc) {
        int s = (kc * 4 + g) ^ (r15 & 7);            // swizzled 32B granule
        const float* src = &reg[r15 * DIM + s * 8];
        float4 lo = *reinterpret_cast<const float4*>(src);       // ds_read_b128
        float4 hi = *reinterpret_cast<const float4*>(src + 4);   // ds_read_b128
        bf16x8 t;
        t[0] = (short)f2bf(lo.x); t[1] = (short)f2bf(lo.y);
        t[2] = (short)f2bf(lo.z); t[3] = (short)f2bf(lo.w);
        t[4] = (short)f2bf(hi.x); t[5] = (short)f2bf(hi.y);
        t[6] = (short)f2bf(hi.z); t[7] = (short)f2bf(hi.w);
        bfr[kc] = t;
    }

    f32x4 acc[4];
    #pragma unroll
    for (int ab = 0; ab < 4; ++ab) acc[ab] = (f32x4){0.f, 0.f, 0.f, 0.f};
    #pragma unroll
    for (int kc = 0; kc < 2; ++kc)
        #pragma unroll
        for (int ab = 0; ab < 4; ++ab)
            acc[ab] = __builtin_amdgcn_mfma_f32_16x16x32_bf16(
                af[kc][ab], bfr[kc], acc[ab], 0, 0, 0);

    // ---- store: full 64B lines per 16-lane group ----
    float4* __restrict__ outp = (float4*)out;
    const long long rg = rowbase + r15;
    #pragma unroll
    for (int ab = 0; ab < 4; ++ab)
        outp[rg * 16 + ab * 4 + g] =
            make_float4(acc[ab][0], acc[ab][1], acc[ab][2], acc[ab][3]);
}

extern "C" void kernel_launch(void* const* d_in, const int* in_sizes, int n_in,
                              void* d_out, int out_size, void* d_ws, size_t ws_size,
                              hipStream_t stream) {
    const float* x = (const float*)d_in[0];
    const float* w = (const float*)d_in[1];
    float* out = (float*)d_out;
    unsigned short* Mt = (unsigned short*)d_ws;   // 8 KB frag-ordered M^T

    int nrows = in_sizes[0] / DIM;                // 1048576
    int nblocks = nrows / ROWS;                   // 16384 (exact)

    build_Mt<<<16, 256, 0, stream>>>(w, Mt);
    gp_main_kernel<<<nblocks, TPB, 0, stream>>>(x, Mt, out);
}

// Round 11
// 103.208 us; speedup vs baseline: 1.1175x; 1.0416x over previous
//
#include <hip/hip_runtime.h>
#include <hip/hip_bf16.h>

// out[b,n] = sum_k x[b,k] * M[k,n],  M[k,n] = sign(k, k^n) * w[k^n]
// P=6,Q=0,R=0 -> metric all +1, sign = reorder parity only.
//
// out^T = M^T (A) @ x^T (B) via mfma_f32_16x16x32_bf16 (layout validated
// round 4, absmax 0.25):
//   A-frag: lane l -> row a=l&15, k=(l>>4)*8+e  (frag-ordered in d_ws)
//   B-frag: lane l -> col b=l&15, k=(l>>4)*8+e  = 8 contiguous k of x row b
//   C/D   : D[m=(l>>4)*4+reg][n=l&15] -> lane's 4 regs = 4 consecutive out
//           cols of one batch row; 16-lane groups complete full 64B lines.
//
// x staged f32 in LDS via global_load_lds dwordx4 DMA (16B width, linear
// dest, pre-swizzled global source - m104/m173), bf16-converted at fragment
// read. 16KB LDS -> 8 blocks/CU = 32 waves/CU (occupancy cap).
//
// FINAL (round 6 optimum). A/B sweep: no-LDS 123.1 / nt-stores 111.1 /
// deep-vmcnt-pipeline 115.3 / barrier-free 107.5 / THIS 102.8 µs.
// ~393MB HBM per replay (L3 serves ~half of x) ~= 65-70% of 6.3TB/s mixed
// ceiling; all structural levers off this point regress.

#define DIM 64
#define TPB 256            // 4 waves
#define ROWS 64            // rows per block; LDS = 64*256B = 16 KB -> 8 blk/CU

typedef __attribute__((ext_vector_type(8))) short  bf16x8;
typedef __attribute__((ext_vector_type(4))) float  f32x4;

typedef const unsigned int __attribute__((address_space(1)))* gu32p;
typedef unsigned int __attribute__((address_space(3)))* su32p;

__device__ __forceinline__ unsigned short f2bf(float v) {
    __hip_bfloat16 hb = __float2bfloat16(v);
    return *reinterpret_cast<unsigned short*>(&hb);
}

// Mt[(kc*4+ab)*64 + lane] = 16B A-fragment slice for mfma block (kc, ab):
// elem e -> A[a = ab*16 + (l&15)][k = kc*32 + (l>>4)*8 + e], A = M^T.
__global__ void build_Mt(const float* __restrict__ w, unsigned short* __restrict__ Mt) {
    int t = threadIdx.x + blockIdx.x * blockDim.x;   // 0..4095
    if (t >= 8 * 64 * 8) return;
    int f  = t >> 9;
    int kc = f >> 2, ab = f & 3;
    int rem = t & 511;
    int l = rem >> 3, e = rem & 7;
    int k = kc * 32 + ((l >> 4) << 3) + e;
    int a = (ab << 4) + (l & 15);
    int j = k ^ a;
    int aa = k >> 1, cnt = 0;
    while (aa) { cnt += __popc(aa & j); aa >>= 1; }
    float v = (cnt & 1) ? -w[j] : w[j];
    Mt[t] = f2bf(v);
}

__global__ __launch_bounds__(TPB, 8)   // 8 blocks/CU = 32 waves/CU (VGPR<=64)
void gp_main_kernel(const float* __restrict__ x,
                    const unsigned short* __restrict__ Mt,
                    float* __restrict__ out) {
    __shared__ float xs[ROWS * DIM];     // 16 KB, f32, granule-swizzled rows

    const int tid  = threadIdx.x;
    const int lane = tid & 63;
    const int wv   = tid >> 6;
    const int r15  = lane & 15;
    const int g    = lane >> 4;          // k-quarter within fragment

    const long long rowbase = (long long)blockIdx.x * ROWS;
    const float4* __restrict__ xin = (const float4*)x;

    // ---- stage: 4x global_load_lds dwordx4 per thread, linear LDS dest ----
    // LDS f4-slot idx: row=idx>>4, granule gr=(idx&15)>>1, half=idx&1;
    // content = source granule c = gr ^ (row&7)  (involution)
    #pragma unroll
    for (int it = 0; it < 4; ++it) {
        int idx  = it * TPB + tid;           // 0..1023 float4 slots
        int row  = idx >> 4;
        int f4   = idx & 15;
        int c    = ((f4 >> 1) ^ (row & 7));
        long long src = (rowbase + row) * 16 + c * 2 + (f4 & 1);
        __builtin_amdgcn_global_load_lds((gu32p)(xin + src),
                                         (su32p)&xs[idx * 4], 16, 0, 0);
    }

    // ---- A-fragments (tiny, L2-resident) while DMA is in flight ----
    bf16x8 af[2][4];
    const bf16x8* __restrict__ Mtv = (const bf16x8*)Mt;
    #pragma unroll
    for (int kc = 0; kc < 2; ++kc)
        #pragma unroll
        for (int ab = 0; ab < 4; ++ab)
            af[kc][ab] = Mtv[(kc * 4 + ab) * 64 + lane];

    __syncthreads();   // compiler drains vmcnt+lgkmcnt before barrier

    // ---- compute: wave wv owns rows [wv*16, wv*16+16) ----
    const int r_loc = wv * 16 + r15;
    bf16x8 bfr[2];
    #pragma unroll
    for (int kc = 0; kc < 2; ++kc) {
        int s = (kc * 4 + g) ^ (r_loc & 7);          // swizzled 32B granule
        const float* src = &xs[r_loc * DIM + s * 8];
        float4 lo = *reinterpret_cast<const float4*>(src);       // ds_read_b128
        float4 hi = *reinterpret_cast<const float4*>(src + 4);   // ds_read_b128
        bf16x8 t;
        t[0] = (short)f2bf(lo.x); t[1] = (short)f2bf(lo.y);
        t[2] = (short)f2bf(lo.z); t[3] = (short)f2bf(lo.w);
        t[4] = (short)f2bf(hi.x); t[5] = (short)f2bf(hi.y);
        t[6] = (short)f2bf(hi.z); t[7] = (short)f2bf(hi.w);
        bfr[kc] = t;
    }

    f32x4 acc[4];
    #pragma unroll
    for (int ab = 0; ab < 4; ++ab) acc[ab] = (f32x4){0.f, 0.f, 0.f, 0.f};
    #pragma unroll
    for (int kc = 0; kc < 2; ++kc)
        #pragma unroll
        for (int ab = 0; ab < 4; ++ab)
            acc[ab] = __builtin_amdgcn_mfma_f32_16x16x32_bf16(
                af[kc][ab], bfr[kc], acc[ab], 0, 0, 0);

    // ---- store: full 64B lines per 16-lane group ----
    float4* __restrict__ outp = (float4*)out;
    const long long rg = rowbase + r_loc;
    #pragma unroll
    for (int ab = 0; ab < 4; ++ab)
        outp[rg * 16 + ab * 4 + g] =
            make_float4(acc[ab][0], acc[ab][1], acc[ab][2], acc[ab][3]);
}

extern "C" void kernel_launch(void* const* d_in, const int* in_sizes, int n_in,
                              void* d_out, int out_size, void* d_ws, size_t ws_size,
                              hipStream_t stream) {
    const float* x = (const float*)d_in[0];
    const float* w = (const float*)d_in[1];
    float* out = (float*)d_out;
    unsigned short* Mt = (unsigned short*)d_ws;   // 8 KB frag-ordered M^T

    int nrows = in_sizes[0] / DIM;                // 1048576
    int nblocks = nrows / ROWS;                   // 16384 (exact)

    build_Mt<<<16, 256, 0, stream>>>(w, Mt);
    gp_main_kernel<<<nblocks, TPB, 0, stream>>>(x, Mt, out);
}